// Round 8
// baseline (4875.855 us; speedup 1.0000x reference)
//
#include <hip/hip_runtime.h>
#include <cstdint>
#include <cstddef>

#define T_STEPS 2048
#define BATCH 64

typedef _Float16 f16;
typedef _Float16 f16x2 __attribute__((ext_vector_type(2)));
typedef _Float16 f16x8 __attribute__((ext_vector_type(8)));
typedef float f32x4 __attribute__((ext_vector_type(4)));
typedef unsigned int uint32;
typedef uint32 u32x4 __attribute__((ext_vector_type(4)));

__device__ __forceinline__ float dot2(uint32 w, uint32 h, float c) {
  f16x2 a = __builtin_bit_cast(f16x2, w);
  f16x2 b = __builtin_bit_cast(f16x2, h);
  return __builtin_amdgcn_fdot2(a, b, c, false);
}

__device__ __forceinline__ float dot8(u32x4 w, u32x4 h, float c) {
  c = dot2(w[0], h[0], c);
  c = dot2(w[1], h[1], c);
  c = dot2(w[2], h[2], c);
  c = dot2(w[3], h[3], c);
  return c;
}

__device__ __forceinline__ uint32 pack2(f16 a, f16 b) {
  f16x2 t; t[0] = a; t[1] = b;
  return __builtin_bit_cast(uint32, t);
}

// ---------------------------------------------------------------- setup ----
__global__ __launch_bounds__(256) void setup_weights(
    const float* __restrict__ Wf, const float* __restrict__ Wi,
    const float* __restrict__ Wo, const float* __restrict__ Wc,
    const float* __restrict__ Wout,
    f16* __restrict__ wx16, f16* __restrict__ wout16)
{
  int id = blockIdx.x * 256 + threadIdx.x;
  const float* WG_[4] = {Wf, Wi, Wo, Wc};
  if (id < 262144) {                       // WxAll f16 [1024][256] (x-part cols)
    int n = id >> 8, k = id & 255;
    int G = n >> 8, j = n & 255;
    wx16[id] = (f16)WG_[G][j * 512 + k];
    return;
  }
  id -= 262144;
  if (id < 65536) { wout16[id] = (f16)Wout[id]; return; }   // Wout f16 [256][256]
}

__global__ __launch_bounds__(256) void setup_state(
    const float* __restrict__ h0, const float* __restrict__ C0,
    f16* __restrict__ hstate, float* __restrict__ c32)
{
  int id = blockIdx.x * 256 + threadIdx.x;
  if (id < 16384) { hstate[id] = (f16)h0[id]; return; }
  id -= 16384;
  if (id < 16384) c32[id] = C0[id];
}

// ---------------------------------------------------------------- GEMM -----
// C[M,N] = A[M,256] @ B[N,256]^T ; 128x128 tile, whole K staged, f16 MFMA.
template<int A_F32, int OUT_F32_BIAS>
__global__ __launch_bounds__(256) void gemm_k(
    const void* __restrict__ Av, const f16* __restrict__ B,
    void* __restrict__ Cv, const float* __restrict__ bias, int N)
{
  constexpr int LDA = 264;
  __shared__ f16 As[128 * 264];
  __shared__ f16 Bs[128 * 264];
  const int tid = threadIdx.x;
  const int m0 = blockIdx.x * 128;
  const int n0 = blockIdx.y * 128;

  if (A_F32) {
    const float* A = (const float*)Av;
    #pragma unroll
    for (int j = 0; j < 32; ++j) {
      int flat = (tid + j * 256) * 4;
      int row = flat >> 8, col = flat & 255;
      const float4 v = *(const float4*)(A + (size_t)(m0 + row) * 256 + col);
      uint2 u; u.x = pack2((f16)v.x, (f16)v.y); u.y = pack2((f16)v.z, (f16)v.w);
      *(uint2*)&As[row * LDA + col] = u;
    }
  } else {
    const f16* A = (const f16*)Av;
    #pragma unroll
    for (int j = 0; j < 32; ++j) {
      int flat = (tid + j * 256) * 4;
      int row = flat >> 8, col = flat & 255;
      *(uint2*)&As[row * LDA + col] = *(const uint2*)(A + (size_t)(m0 + row) * 256 + col);
    }
  }
  #pragma unroll
  for (int j = 0; j < 32; ++j) {
    int flat = (tid + j * 256) * 4;
    int row = flat >> 8, col = flat & 255;
    *(uint2*)&Bs[row * LDA + col] = *(const uint2*)(B + (size_t)(n0 + row) * 256 + col);
  }
  __syncthreads();

  const int wave = tid >> 6, l = tid & 63;
  const int wr = wave >> 1, wc = wave & 1;
  const int lr = l & 15, lq = l >> 4;

  f32x4 acc[4][4] = {};
  #pragma unroll
  for (int kk = 0; kk < 8; ++kk) {
    f16x8 a[4], b[4];
    #pragma unroll
    for (int mi = 0; mi < 4; ++mi)
      a[mi] = *(const f16x8*)&As[(64 * wr + 16 * mi + lr) * LDA + kk * 32 + lq * 8];
    #pragma unroll
    for (int ni = 0; ni < 4; ++ni)
      b[ni] = *(const f16x8*)&Bs[(64 * wc + 16 * ni + lr) * LDA + kk * 32 + lq * 8];
    #pragma unroll
    for (int mi = 0; mi < 4; ++mi)
      #pragma unroll
      for (int ni = 0; ni < 4; ++ni)
        acc[mi][ni] = __builtin_amdgcn_mfma_f32_16x16x32_f16(a[mi], b[ni], acc[mi][ni], 0, 0, 0);
  }

  #pragma unroll
  for (int mi = 0; mi < 4; ++mi) {
    #pragma unroll
    for (int ni = 0; ni < 4; ++ni) {
      int col = n0 + 64 * wc + 16 * ni + lr;
      float bv = 0.f;
      if (OUT_F32_BIAS) bv = bias[col];
      #pragma unroll
      for (int v = 0; v < 4; ++v) {
        int row = m0 + 64 * wr + 16 * mi + lq * 4 + v;
        if (OUT_F32_BIAS) ((float*)Cv)[(size_t)row * N + col] = acc[mi][ni][v] + bv;
        else              ((f16*)Cv)[(size_t)row * N + col] = (f16)acc[mi][ni][v];
      }
    }
  }
}

// --------------------------------------------------------- persistent LSTM -
// 64 WGs x 512 thr; WG r owns batch row r ENTIRELY -> zero cross-WG traffic.
// Thread (p = tid>>8, jj = tid&255) owns gate outputs G0=2p, G1=2p+1 for
// column jj. Per output, K=256 h-weights: K 0..231 in 29 u32x4 VGPRs
// (2x116 = 232 VGPRs), K 232..255 in LDS (48KB, conflict-free layout).
// h lives in a 512B LDS array updated in place; C in registers.
// Per step: dot chain -> barrier -> pointwise update -> barrier. No atomics.
__global__ __launch_bounds__(512, 2) void lstm_persist(
    const float* __restrict__ Wf, const float* __restrict__ Wi,
    const float* __restrict__ Wo, const float* __restrict__ Wc,
    const float* __restrict__ bf, const float* __restrict__ bi,
    const float* __restrict__ bo, const float* __restrict__ bc,
    const f16* __restrict__ xproj, f16* __restrict__ hstate,
    float* __restrict__ c32, float* __restrict__ hid_out,
    f16* __restrict__ h16c, float* __restrict__ cf_out, int t0, int Tc)
{
  __shared__ u32x4 wlds[3072];                              // 48KB weight tail
  __shared__ uint32 h_lds[128] __attribute__((aligned(16))); // h (256 f16)
  __shared__ float part[1024];                               // gate pre-acts

  const int tid = threadIdx.x;
  const int r = blockIdx.x;
  const int p = tid >> 8, jj = tid & 255;
  const int G0 = p * 2, G1 = p * 2 + 1;

  const float* WA = (p == 0) ? Wf : Wo;
  const float* WB = (p == 0) ? Wi : Wc;
  const float* bA = (p == 0) ? bf : bo;
  const float* bB = (p == 0) ? bi : bc;

  // ---- one-time: pack h-part weights (f32 -> f16x2) ----
  u32x4 wva[29], wvb[29];
  {
    const float* ra = WA + (size_t)jj * 512 + 256;
    const float* rb = WB + (size_t)jj * 512 + 256;
    #pragma unroll
    for (int kq = 0; kq < 29; ++kq) {
      u32x4 a, b;
      #pragma unroll
      for (int kk = 0; kk < 4; ++kk) {
        const float2 fa = *(const float2*)(ra + kq * 8 + kk * 2);
        const float2 fb = *(const float2*)(rb + kq * 8 + kk * 2);
        a[kk] = pack2((f16)fa.x, (f16)fa.y);
        b[kk] = pack2((f16)fb.x, (f16)fb.y);
      }
      wva[kq] = a; wvb[kq] = b;
    }
    #pragma unroll
    for (int kq = 0; kq < 3; ++kq) {
      u32x4 a, b;
      #pragma unroll
      for (int kk = 0; kk < 4; ++kk) {
        const float2 fa = *(const float2*)(ra + 232 + kq * 8 + kk * 2);
        const float2 fb = *(const float2*)(rb + 232 + kq * 8 + kk * 2);
        a[kk] = pack2((f16)fa.x, (f16)fa.y);
        b[kk] = pack2((f16)fb.x, (f16)fb.y);
      }
      wlds[(kq * 2 + 0) * 512 + tid] = a;
      wlds[(kq * 2 + 1) * 512 + tid] = b;
    }
  }
  const float b0 = bA[jj], b1 = bB[jj];

  float Creg = 0.f;
  if (tid < 256) Creg = c32[r * 256 + tid];
  if (tid < 128) h_lds[tid] = ((const uint32*)hstate)[r * 128 + tid];
  __syncthreads();

  for (int tl = 0; tl < Tc; ++tl) {
    const int gt = t0 + tl;

    // x-projection loads issue here, consumed at the end of the dot chain
    const f16* xrow = xproj + ((size_t)tl * 64 + r) * 1024;
    const float xp0 = (float)xrow[G0 * 256 + jj];
    const float xp1 = (float)xrow[G1 * 256 + jj];

    float acc0 = 0.f, acc1 = 0.f;
    #pragma unroll
    for (int kq = 0; kq < 29; ++kq) {
      const u32x4 hh = *(const u32x4*)&h_lds[kq * 4];
      acc0 = dot8(wva[kq], hh, acc0);
      acc1 = dot8(wvb[kq], hh, acc1);
    }
    #pragma unroll
    for (int kq = 0; kq < 3; ++kq) {
      const u32x4 hh = *(const u32x4*)&h_lds[(29 + kq) * 4];
      const u32x4 wa = wlds[(kq * 2 + 0) * 512 + tid];
      const u32x4 wb = wlds[(kq * 2 + 1) * 512 + tid];
      acc0 = dot8(wa, hh, acc0);
      acc1 = dot8(wb, hh, acc1);
    }
    part[G0 * 256 + jj] = acc0 + xp0 + b0;
    part[G1 * 256 + jj] = acc1 + xp1 + b1;
    __syncthreads();

    // pointwise update: thread tid<256 owns column j=tid
    if (tid < 256) {
      const float pf = part[tid];
      const float pi = part[256 + tid];
      const float po = part[512 + tid];
      const float pc = part[768 + tid];
      const float f_ = __builtin_amdgcn_rcpf(1.f + __expf(-pf));
      const float i_ = __builtin_amdgcn_rcpf(1.f + __expf(-pi));
      const float o_ = __builtin_amdgcn_rcpf(1.f + __expf(-po));
      const float cb = 1.f - 2.f * __builtin_amdgcn_rcpf(__expf(2.f * pc) + 1.f);
      const float Cn = f_ * Creg + i_ * cb;
      Creg = Cn;
      const float th = 1.f - 2.f * __builtin_amdgcn_rcpf(__expf(2.f * Cn) + 1.f);
      const float hn = o_ * th;
      hid_out[((size_t)gt * 64 + r) * 256 + tid] = hn;
      const f16 h16v = (f16)hn;
      ((unsigned short*)h_lds)[tid] = __builtin_bit_cast(unsigned short, h16v);
      h16c[((size_t)tl * 64 + r) * 256 + tid] = h16v;
      if (gt == T_STEPS - 1) cf_out[r * 256 + tid] = Cn;
    }
    __syncthreads();
  }

  if (tid < 256) c32[r * 256 + tid] = Creg;
  if (tid < 128) ((uint32*)hstate)[r * 128 + tid] = h_lds[tid];
}

// ---------------------------------------------------------------- host -----
extern "C" void kernel_launch(void* const* d_in, const int* in_sizes, int n_in,
                              void* d_out, int out_size, void* d_ws, size_t ws_size,
                              hipStream_t stream)
{
  const float* x    = (const float*)d_in[0];
  const float* h0   = (const float*)d_in[1];
  const float* C0   = (const float*)d_in[2];
  const float* Wf   = (const float*)d_in[3];
  const float* bf   = (const float*)d_in[4];
  const float* Wi   = (const float*)d_in[5];
  const float* bi   = (const float*)d_in[6];
  const float* Wo   = (const float*)d_in[7];
  const float* bo   = (const float*)d_in[8];
  const float* Wc   = (const float*)d_in[9];
  const float* bc   = (const float*)d_in[10];
  const float* Wout = (const float*)d_in[11];
  const float* bout = (const float*)d_in[12];
  float* out = (float*)d_out;

  char* w = (char*)d_ws;
  f16*    wx16   = (f16*)w;    w += (size_t)1024 * 256 * 2;
  f16*    wout16 = (f16*)w;    w += (size_t)256 * 256 * 2;
  f16*    hstate = (f16*)w;    w += (size_t)64 * 256 * 2;
  float*  c32    = (float*)w;  w += (size_t)64 * 256 * 4;
  const size_t fixedB = (size_t)(w - (char*)d_ws);

  int Tc = 2;
  const int cands[] = {2048, 1024, 512, 256, 128, 64, 32, 16, 8, 4, 2};
  for (int c : cands) {
    if (fixedB + (size_t)c * 163840 <= ws_size) { Tc = c; break; }
  }

  f16* xproj = (f16*)w;
  f16* h16c  = (f16*)(w + (size_t)Tc * 64 * 1024 * 2);

  setup_weights<<<1280, 256, 0, stream>>>(Wf, Wi, Wo, Wc, Wout, wx16, wout16);
  setup_state<<<128, 256, 0, stream>>>(h0, C0, hstate, c32);

  float* hid_out = out + (size_t)T_STEPS * 64 * 256;
  float* cf_out  = out + (size_t)2 * T_STEPS * 64 * 256;

  for (int t0 = 0; t0 < T_STEPS; t0 += Tc) {
    gemm_k<1, 0><<<dim3(Tc * 64 / 128, 8), 256, 0, stream>>>(
        x + (size_t)t0 * 64 * 256, wx16, xproj, nullptr, 1024);
    lstm_persist<<<64, 512, 0, stream>>>(Wf, Wi, Wo, Wc, bf, bi, bo, bc,
                                         xproj, hstate, c32,
                                         hid_out, h16c, cf_out, t0, Tc);
    gemm_k<0, 1><<<dim3(Tc * 64 / 128, 2), 256, 0, stream>>>(
        h16c, wout16, out + (size_t)t0 * 64 * 256, bout, 256);
  }
}

// Round 9
// 3651.034 us; speedup vs baseline: 1.3355x; 1.3355x over previous
//
#include <hip/hip_runtime.h>
#include <cstdint>
#include <cstddef>

#define T_STEPS 2048
#define BATCH 64

typedef _Float16 f16;
typedef _Float16 f16x2 __attribute__((ext_vector_type(2)));
typedef _Float16 f16x8 __attribute__((ext_vector_type(8)));
typedef float f32x4 __attribute__((ext_vector_type(4)));
typedef unsigned int uint32;
typedef uint32 u32x4 __attribute__((ext_vector_type(4)));

#if defined(__has_attribute)
#  if __has_attribute(amdgpu_waves_per_eu)
#    define WPEU22 __attribute__((amdgpu_waves_per_eu(2, 2)))
#  else
#    define WPEU22
#  endif
#else
#  define WPEU22
#endif

__device__ __forceinline__ float dot2(uint32 w, uint32 h, float c) {
  f16x2 a = __builtin_bit_cast(f16x2, w);
  f16x2 b = __builtin_bit_cast(f16x2, h);
  return __builtin_amdgcn_fdot2(a, b, c, false);
}

__device__ __forceinline__ float dot8(u32x4 w, u32x4 h, float c) {
  c = dot2(w[0], h[0], c);
  c = dot2(w[1], h[1], c);
  c = dot2(w[2], h[2], c);
  c = dot2(w[3], h[3], c);
  return c;
}

__device__ __forceinline__ uint32 pack2(f16 a, f16 b) {
  f16x2 t; t[0] = a; t[1] = b;
  return __builtin_bit_cast(uint32, t);
}

// pack 8 consecutive f32 into u32x4 of f16x2
__device__ __forceinline__ u32x4 packrow(const float* p) {
  u32x4 v;
  #pragma unroll
  for (int kk = 0; kk < 4; ++kk) {
    const float2 f = *(const float2*)(p + kk * 2);
    v[kk] = pack2((f16)f.x, (f16)f.y);
  }
  return v;
}

// ---------------------------------------------------------------- setup ----
__global__ __launch_bounds__(256) void setup_weights(
    const float* __restrict__ Wf, const float* __restrict__ Wi,
    const float* __restrict__ Wo, const float* __restrict__ Wc,
    const float* __restrict__ Wout,
    f16* __restrict__ wx16, f16* __restrict__ wout16)
{
  int id = blockIdx.x * 256 + threadIdx.x;
  const float* WG_[4] = {Wf, Wi, Wo, Wc};
  if (id < 262144) {                       // WxAll f16 [1024][256] (x-part cols)
    int n = id >> 8, k = id & 255;
    int G = n >> 8, j = n & 255;
    wx16[id] = (f16)WG_[G][j * 512 + k];
    return;
  }
  id -= 262144;
  if (id < 65536) { wout16[id] = (f16)Wout[id]; return; }   // Wout f16 [256][256]
}

__global__ __launch_bounds__(256) void setup_state(
    const float* __restrict__ h0, const float* __restrict__ C0,
    f16* __restrict__ hstate, float* __restrict__ c32)
{
  int id = blockIdx.x * 256 + threadIdx.x;
  if (id < 16384) { hstate[id] = (f16)h0[id]; return; }
  id -= 16384;
  if (id < 16384) c32[id] = C0[id];
}

// ---------------------------------------------------------------- GEMM -----
// C[M,N] = A[M,256] @ B[N,256]^T ; 128x128 tile, whole K staged, f16 MFMA.
template<int A_F32, int OUT_F32_BIAS>
__global__ __launch_bounds__(256) void gemm_k(
    const void* __restrict__ Av, const f16* __restrict__ B,
    void* __restrict__ Cv, const float* __restrict__ bias, int N)
{
  constexpr int LDA = 264;
  __shared__ f16 As[128 * 264];
  __shared__ f16 Bs[128 * 264];
  const int tid = threadIdx.x;
  const int m0 = blockIdx.x * 128;
  const int n0 = blockIdx.y * 128;

  if (A_F32) {
    const float* A = (const float*)Av;
    #pragma unroll
    for (int j = 0; j < 32; ++j) {
      int flat = (tid + j * 256) * 4;
      int row = flat >> 8, col = flat & 255;
      const float4 v = *(const float4*)(A + (size_t)(m0 + row) * 256 + col);
      uint2 u; u.x = pack2((f16)v.x, (f16)v.y); u.y = pack2((f16)v.z, (f16)v.w);
      *(uint2*)&As[row * LDA + col] = u;
    }
  } else {
    const f16* A = (const f16*)Av;
    #pragma unroll
    for (int j = 0; j < 32; ++j) {
      int flat = (tid + j * 256) * 4;
      int row = flat >> 8, col = flat & 255;
      *(uint2*)&As[row * LDA + col] = *(const uint2*)(A + (size_t)(m0 + row) * 256 + col);
    }
  }
  #pragma unroll
  for (int j = 0; j < 32; ++j) {
    int flat = (tid + j * 256) * 4;
    int row = flat >> 8, col = flat & 255;
    *(uint2*)&Bs[row * LDA + col] = *(const uint2*)(B + (size_t)(n0 + row) * 256 + col);
  }
  __syncthreads();

  const int wave = tid >> 6, l = tid & 63;
  const int wr = wave >> 1, wc = wave & 1;
  const int lr = l & 15, lq = l >> 4;

  f32x4 acc[4][4] = {};
  #pragma unroll
  for (int kk = 0; kk < 8; ++kk) {
    f16x8 a[4], b[4];
    #pragma unroll
    for (int mi = 0; mi < 4; ++mi)
      a[mi] = *(const f16x8*)&As[(64 * wr + 16 * mi + lr) * LDA + kk * 32 + lq * 8];
    #pragma unroll
    for (int ni = 0; ni < 4; ++ni)
      b[ni] = *(const f16x8*)&Bs[(64 * wc + 16 * ni + lr) * LDA + kk * 32 + lq * 8];
    #pragma unroll
    for (int mi = 0; mi < 4; ++mi)
      #pragma unroll
      for (int ni = 0; ni < 4; ++ni)
        acc[mi][ni] = __builtin_amdgcn_mfma_f32_16x16x32_f16(a[mi], b[ni], acc[mi][ni], 0, 0, 0);
  }

  #pragma unroll
  for (int mi = 0; mi < 4; ++mi) {
    #pragma unroll
    for (int ni = 0; ni < 4; ++ni) {
      int col = n0 + 64 * wc + 16 * ni + lr;
      float bv = 0.f;
      if (OUT_F32_BIAS) bv = bias[col];
      #pragma unroll
      for (int v = 0; v < 4; ++v) {
        int row = m0 + 64 * wr + 16 * mi + lq * 4 + v;
        if (OUT_F32_BIAS) ((float*)Cv)[(size_t)row * N + col] = acc[mi][ni][v] + bv;
        else              ((f16*)Cv)[(size_t)row * N + col] = (f16)acc[mi][ni][v];
      }
    }
  }
}

// --------------------------------------------------------- persistent LSTM -
// 64 WGs x 512 thr; WG r owns batch row r ENTIRELY -> zero cross-WG traffic.
// Thread (p=tid>>8, jj=tid&255) owns gate outputs G0=2p, G1=2p+1 for column
// jj. Weights: K 0..207 in 52 NAMED u32x4 VGPRs (208 regs, macro-generated --
// no arrays, rule-#20-proof), K 208..255 in 96KB LDS. amdgpu_waves_per_eu(2,2)
// pins 2 waves/SIMD so the allocator may use up to 256 VGPRs (R8's 128-cap
// spilled 232 regs of weights to scratch = the 2.24us/step regression).
// h in 512B LDS updated in place; C in registers; two barriers/step.
#define RL26(M) M(0) M(1) M(2) M(3) M(4) M(5) M(6) M(7) M(8) M(9) M(10) M(11) \
  M(12) M(13) M(14) M(15) M(16) M(17) M(18) M(19) M(20) M(21) M(22) M(23) M(24) M(25)
#define RL6(M) M(0) M(1) M(2) M(3) M(4) M(5)

__global__ __launch_bounds__(512) WPEU22 void lstm_persist(
    const float* __restrict__ Wf, const float* __restrict__ Wi,
    const float* __restrict__ Wo, const float* __restrict__ Wc,
    const float* __restrict__ bf, const float* __restrict__ bi,
    const float* __restrict__ bo, const float* __restrict__ bc,
    const f16* __restrict__ xproj, f16* __restrict__ hstate,
    float* __restrict__ c32, float* __restrict__ hid_out,
    f16* __restrict__ h16c, float* __restrict__ cf_out, int t0, int Tc)
{
  __shared__ u32x4 wlds[6144];                               // 96KB weight tail
  __shared__ uint32 h_lds[128] __attribute__((aligned(16))); // h (256 f16)
  __shared__ float part[1024];                               // gate pre-acts

  const int tid = threadIdx.x;
  const int r = blockIdx.x;
  const int p = tid >> 8, jj = tid & 255;
  const int G0 = p * 2, G1 = p * 2 + 1;

  const float* WA = (p == 0) ? Wf : Wo;
  const float* WB = (p == 0) ? Wi : Wc;
  const float* bA = (p == 0) ? bf : bo;
  const float* bB = (p == 0) ? bi : bc;

  const float* ra = WA + (size_t)jj * 512 + 256;
  const float* rb = WB + (size_t)jj * 512 + 256;

  // ---- one-time: named weight registers (K 0..207) ----
#define DECLW(i) u32x4 wa##i, wb##i;
  RL26(DECLW)
#undef DECLW
#define LOADW(i) wa##i = packrow(ra + (i) * 8); wb##i = packrow(rb + (i) * 8);
  RL26(LOADW)
#undef LOADW
  // ---- weight tail (K 208..255) into LDS ----
#define TSTORE(i) \
  wlds[((i) * 2 + 0) * 512 + tid] = packrow(ra + 208 + (i) * 8); \
  wlds[((i) * 2 + 1) * 512 + tid] = packrow(rb + 208 + (i) * 8);
  RL6(TSTORE)
#undef TSTORE

  const float b0 = bA[jj], b1 = bB[jj];

  float Creg = 0.f;
  if (tid < 256) Creg = c32[r * 256 + tid];
  if (tid < 128) h_lds[tid] = ((const uint32*)hstate)[r * 128 + tid];
  __syncthreads();

  for (int tl = 0; tl < Tc; ++tl) {
    const int gt = t0 + tl;

    // x-projection loads issue here, consumed at the end of the dot chain
    const f16* xrow = xproj + ((size_t)tl * 64 + r) * 1024;
    const float xp0 = (float)xrow[G0 * 256 + jj];
    const float xp1 = (float)xrow[G1 * 256 + jj];

    // opaque tid: prevents hoisting the loop-invariant wlds reads into VGPRs
    int otid;
    asm volatile("v_mov_b32 %0, %1" : "=v"(otid) : "v"(tid));

    float acc0 = 0.f, acc1 = 0.f;
#define DOTW(i) { const u32x4 hh = *(const u32x4*)&h_lds[(i) * 4]; \
                  acc0 = dot8(wa##i, hh, acc0); acc1 = dot8(wb##i, hh, acc1); }
    RL26(DOTW)
#undef DOTW
#define TDOT(i) { const u32x4 hh = *(const u32x4*)&h_lds[(26 + (i)) * 4]; \
                  const u32x4 ta = wlds[((i) * 2 + 0) * 512 + otid]; \
                  const u32x4 tb = wlds[((i) * 2 + 1) * 512 + otid]; \
                  acc0 = dot8(ta, hh, acc0); acc1 = dot8(tb, hh, acc1); }
    RL6(TDOT)
#undef TDOT

    part[G0 * 256 + jj] = acc0 + xp0 + b0;
    part[G1 * 256 + jj] = acc1 + xp1 + b1;
    __syncthreads();

    // pointwise update: thread tid<256 owns column j=tid
    if (tid < 256) {
      const float pf = part[tid];
      const float pi = part[256 + tid];
      const float po = part[512 + tid];
      const float pc = part[768 + tid];
      const float f_ = __builtin_amdgcn_rcpf(1.f + __expf(-pf));
      const float i_ = __builtin_amdgcn_rcpf(1.f + __expf(-pi));
      const float o_ = __builtin_amdgcn_rcpf(1.f + __expf(-po));
      const float cb = 1.f - 2.f * __builtin_amdgcn_rcpf(__expf(2.f * pc) + 1.f);
      const float Cn = f_ * Creg + i_ * cb;
      Creg = Cn;
      const float th = 1.f - 2.f * __builtin_amdgcn_rcpf(__expf(2.f * Cn) + 1.f);
      const float hn = o_ * th;
      hid_out[((size_t)gt * 64 + r) * 256 + tid] = hn;
      const f16 h16v = (f16)hn;
      ((unsigned short*)h_lds)[tid] = __builtin_bit_cast(unsigned short, h16v);
      h16c[((size_t)tl * 64 + r) * 256 + tid] = h16v;
      if (gt == T_STEPS - 1) cf_out[r * 256 + tid] = Cn;
    }
    __syncthreads();
  }

  if (tid < 256) c32[r * 256 + tid] = Creg;
  if (tid < 128) ((uint32*)hstate)[r * 128 + tid] = h_lds[tid];
}

// ---------------------------------------------------------------- host -----
extern "C" void kernel_launch(void* const* d_in, const int* in_sizes, int n_in,
                              void* d_out, int out_size, void* d_ws, size_t ws_size,
                              hipStream_t stream)
{
  const float* x    = (const float*)d_in[0];
  const float* h0   = (const float*)d_in[1];
  const float* C0   = (const float*)d_in[2];
  const float* Wf   = (const float*)d_in[3];
  const float* bf   = (const float*)d_in[4];
  const float* Wi   = (const float*)d_in[5];
  const float* bi   = (const float*)d_in[6];
  const float* Wo   = (const float*)d_in[7];
  const float* bo   = (const float*)d_in[8];
  const float* Wc   = (const float*)d_in[9];
  const float* bc   = (const float*)d_in[10];
  const float* Wout = (const float*)d_in[11];
  const float* bout = (const float*)d_in[12];
  float* out = (float*)d_out;

  char* w = (char*)d_ws;
  f16*    wx16   = (f16*)w;    w += (size_t)1024 * 256 * 2;
  f16*    wout16 = (f16*)w;    w += (size_t)256 * 256 * 2;
  f16*    hstate = (f16*)w;    w += (size_t)64 * 256 * 2;
  float*  c32    = (float*)w;  w += (size_t)64 * 256 * 4;
  const size_t fixedB = (size_t)(w - (char*)d_ws);

  int Tc = 2;
  const int cands[] = {2048, 1024, 512, 256, 128, 64, 32, 16, 8, 4, 2};
  for (int c : cands) {
    if (fixedB + (size_t)c * 163840 <= ws_size) { Tc = c; break; }
  }

  f16* xproj = (f16*)w;
  f16* h16c  = (f16*)(w + (size_t)Tc * 64 * 1024 * 2);

  setup_weights<<<1280, 256, 0, stream>>>(Wf, Wi, Wo, Wc, Wout, wx16, wout16);
  setup_state<<<128, 256, 0, stream>>>(h0, C0, hstate, c32);

  float* hid_out = out + (size_t)T_STEPS * 64 * 256;
  float* cf_out  = out + (size_t)2 * T_STEPS * 64 * 256;

  for (int t0 = 0; t0 < T_STEPS; t0 += Tc) {
    gemm_k<1, 0><<<dim3(Tc * 64 / 128, 8), 256, 0, stream>>>(
        x + (size_t)t0 * 64 * 256, wx16, xproj, nullptr, 1024);
    lstm_persist<<<64, 512, 0, stream>>>(Wf, Wi, Wo, Wc, bf, bi, bo, bc,
                                         xproj, hstate, c32,
                                         hid_out, h16c, cf_out, t0, Tc);
    gemm_k<0, 1><<<dim3(Tc * 64 / 128, 2), 256, 0, stream>>>(
        h16c, wout16, out + (size_t)t0 * 64 * 256, bout, 256);
  }
}